// Round 1
// baseline (2837.399 us; speedup 1.0000x reference)
//
#include <hip/hip_runtime.h>

// Problem constants (B,S,D,K,F) = (4, 2048, 1024, 4, 4096)
static constexpr int Bb = 4;
static constexpr int Ss = 2048;
static constexpr int Dd = 1024;
static constexpr int Ff = 4096;
static constexpr int Mm = Bb * Ss;              // 8192 rows
static constexpr size_t ND = (size_t)Mm * Dd;   // 8388608 elements per [B,S,D] tensor

// ---------------- RMSNorm: one block per row, 256 threads * float4 ----------
__global__ __launch_bounds__(256) void rmsnorm_k(const float* __restrict__ x,
                                                 const float* __restrict__ w,
                                                 float* __restrict__ out) {
  int row = blockIdx.x;
  const float4* xr = (const float4*)(x + (size_t)row * Dd);
  float4* orow = (float4*)(out + (size_t)row * Dd);
  int t = threadIdx.x;
  float4 v = xr[t];
  float ss = v.x * v.x + v.y * v.y + v.z * v.z + v.w * v.w;
#pragma unroll
  for (int off = 32; off > 0; off >>= 1) ss += __shfl_down(ss, off, 64);
  __shared__ float sb[4];
  if ((t & 63) == 0) sb[t >> 6] = ss;
  __syncthreads();
  float tot = sb[0] + sb[1] + sb[2] + sb[3];
  float sc = rsqrtf(tot * (1.0f / (float)Dd) + 1e-6f);
  float4 wv = ((const float4*)w)[t];
  float4 o;
  o.x = v.x * sc * wv.x;
  o.y = v.y * sc * wv.y;
  o.z = v.z * sc * wv.z;
  o.w = v.w * sc * wv.w;
  orow[t] = o;
}

// ---------------- Causal depthwise conv (K=4 taps) → concat[:, 0:D] ---------
__global__ __launch_bounds__(256) void conv_k(const float* __restrict__ xn,
                                              const float* __restrict__ kern,
                                              const float* __restrict__ bias,
                                              float* __restrict__ outC) {
  size_t i = (size_t)blockIdx.x * 256 + threadIdx.x;   // over Mm*Dd
  int d = (int)(i & (Dd - 1));
  int m = (int)(i >> 10);
  int t = m & (Ss - 1);
  float4 kv = ((const float4*)kern)[d];                // kernel[d][0..3]
  float acc = bias[d] + kv.x * xn[i];
  if (t >= 1) acc += kv.y * xn[i - Dd];
  if (t >= 2) acc += kv.z * xn[i - 2 * Dd];
  if (t >= 3) acc += kv.w * xn[i - 3 * Dd];
  outC[(size_t)m * (2 * Dd) + d] = acc;
}

// ---------------- fp32 SGEMM: 128x128 tile, BK=8, 256 thr, 2x2 4x4 subtiles -
// MODE bit0: +bias[col]   bit1: gelu(tanh approx)   bit2: +extra[row*N+col]
template <int MODE>
__global__ __launch_bounds__(256) void sgemm_k(const float* __restrict__ A,
                                               const float* __restrict__ Bm,
                                               float* __restrict__ C,
                                               int M, int N, int K,
                                               const float* __restrict__ bias,
                                               const float* __restrict__ extra) {
  __shared__ float As[8][128];   // transposed: As[k][m]
  __shared__ float Bs[8][128];
  const int tid = threadIdx.x;
  const int bm = blockIdx.y * 128;
  const int bn = blockIdx.x * 128;
  const int tx = tid & 15;       // 16 col groups
  const int ty = tid >> 4;       // 16 row groups
  const int ar = tid >> 1;       // A-load row 0..127
  const int ac = (tid & 1) * 4;  // A-load col 0 or 4
  const int br = tid >> 5;       // B-load k 0..7
  const int bc = (tid & 31) * 4; // B-load col 0..124

  float acc[2][2][4][4];
#pragma unroll
  for (int a0 = 0; a0 < 2; a0++)
#pragma unroll
    for (int b0 = 0; b0 < 2; b0++)
#pragma unroll
      for (int i = 0; i < 4; i++)
#pragma unroll
        for (int j = 0; j < 4; j++) acc[a0][b0][i][j] = 0.0f;

  const float* Ap = A + (size_t)(bm + ar) * K + ac;
  const float* Bp = Bm + (size_t)br * N + bn + bc;

  for (int k0 = 0; k0 < K; k0 += 8) {
    float4 av = *(const float4*)Ap;  Ap += 8;
    float4 bv = *(const float4*)Bp;  Bp += (size_t)8 * N;
    __syncthreads();               // previous iter done reading LDS
    As[ac + 0][ar] = av.x;
    As[ac + 1][ar] = av.y;
    As[ac + 2][ar] = av.z;
    As[ac + 3][ar] = av.w;
    *(float4*)&Bs[br][bc] = bv;
    __syncthreads();
#pragma unroll
    for (int kk = 0; kk < 8; kk++) {
      float a0[4], a1[4], b0[4], b1[4];
      *(float4*)a0 = *(const float4*)&As[kk][ty * 4];
      *(float4*)a1 = *(const float4*)&As[kk][64 + ty * 4];
      *(float4*)b0 = *(const float4*)&Bs[kk][tx * 4];
      *(float4*)b1 = *(const float4*)&Bs[kk][64 + tx * 4];
#pragma unroll
      for (int i = 0; i < 4; i++) {
#pragma unroll
        for (int j = 0; j < 4; j++) {
          acc[0][0][i][j] = fmaf(a0[i], b0[j], acc[0][0][i][j]);
          acc[0][1][i][j] = fmaf(a0[i], b1[j], acc[0][1][i][j]);
          acc[1][0][i][j] = fmaf(a1[i], b0[j], acc[1][0][i][j]);
          acc[1][1][i][j] = fmaf(a1[i], b1[j], acc[1][1][i][j]);
        }
      }
    }
  }

#pragma unroll
  for (int si = 0; si < 2; si++) {
#pragma unroll
    for (int i = 0; i < 4; i++) {
      int row = bm + si * 64 + ty * 4 + i;
#pragma unroll
      for (int sj = 0; sj < 2; sj++) {
        int col = bn + sj * 64 + tx * 4;
        float r[4];
#pragma unroll
        for (int j = 0; j < 4; j++) r[j] = acc[si][sj][i][j];
        if (MODE & 1) {
#pragma unroll
          for (int j = 0; j < 4; j++) r[j] += bias[col + j];
        }
        if (MODE & 2) {
#pragma unroll
          for (int j = 0; j < 4; j++) {
            float v = r[j];
            float c = v + 0.044715f * v * v * v;
            r[j] = 0.5f * v * (1.0f + tanhf(0.7978845608028654f * c));
          }
        }
        if (MODE & 4) {
#pragma unroll
          for (int j = 0; j < 4; j++) r[j] += extra[(size_t)row * N + col + j];
        }
        float4 o;
        o.x = r[0]; o.y = r[1]; o.z = r[2]; o.w = r[3];
        *(float4*)&C[(size_t)row * N + col] = o;
      }
    }
  }
}

// ---------------- RG-LRU gating: gpre→u, apre→a (in place) ------------------
__global__ __launch_bounds__(256) void gating_k(float* __restrict__ gpre,
                                                float* __restrict__ apre,
                                                const float* __restrict__ xn,
                                                const float* __restrict__ lam) {
  size_t i = (size_t)blockIdx.x * 256 + threadIdx.x;
  int d = (int)(i & (Dd - 1));
  float g = 1.0f / (1.0f + expf(-gpre[i]));
  float sa = 1.0f / (1.0f + expf(-apre[i]));
  float l = lam[d];
  float sp = fmaxf(l, 0.0f) + log1pf(expf(-fabsf(l)));  // stable softplus
  float a = expf(-8.0f * sp * sa);
  float u = sqrtf(fmaxf(1.0f - a * a, 0.0f)) * g * xn[i];
  gpre[i] = u;
  apre[i] = a;
}

// ---------------- Sequential scan: 1 thread per (b,e), unroll 4 -------------
__global__ __launch_bounds__(64) void scan_k(const float* __restrict__ ab,
                                             const float* __restrict__ ub,
                                             float* __restrict__ outC) {
  int ch = blockIdx.x * 64 + threadIdx.x;  // 0..4095
  int b = ch >> 10;
  int e = ch & (Dd - 1);
  size_t base = (size_t)b * Ss * Dd + e;
  size_t ob = (size_t)b * Ss * (2 * Dd) + Dd + e;
  float h = 0.0f;
  for (int t = 0; t < Ss; t += 4) {
    size_t idx = base + (size_t)t * Dd;
    float a0 = ab[idx], a1 = ab[idx + Dd], a2 = ab[idx + 2 * Dd], a3 = ab[idx + 3 * Dd];
    float u0 = ub[idx], u1 = ub[idx + Dd], u2 = ub[idx + 2 * Dd], u3 = ub[idx + 3 * Dd];
    size_t o = ob + (size_t)t * (2 * Dd);
    h = fmaf(a0, h, u0); outC[o] = h;
    h = fmaf(a1, h, u1); outC[o + 2 * Dd] = h;
    h = fmaf(a2, h, u2); outC[o + 4 * Dd] = h;
    h = fmaf(a3, h, u3); outC[o + 6 * Dd] = h;
  }
}

// ---------------- velocity update (mixer buf becomes x_new, in place) -------
__global__ __launch_bounds__(256) void vel_k(float* __restrict__ mixer_xnew,
                                             const float* __restrict__ velocity,
                                             const float* __restrict__ x,
                                             const float* __restrict__ log_beta,
                                             float* __restrict__ vel_out) {
  size_t i = (size_t)blockIdx.x * 256 + threadIdx.x;
  int d = (int)(i & (Dd - 1));
  float beta = 1.0f / (1.0f + expf(-log_beta[d]));
  float vn = fmaf(beta, velocity[i], mixer_xnew[i]);
  vel_out[i] = vn;
  mixer_xnew[i] = x[i] + vn;   // x_new
}

extern "C" void kernel_launch(void* const* d_in, const int* in_sizes, int n_in,
                              void* d_out, int out_size, void* d_ws, size_t ws_size,
                              hipStream_t stream) {
  const float* x        = (const float*)d_in[0];
  const float* velocity = (const float*)d_in[1];
  const float* pre_w    = (const float*)d_in[2];
  const float* conv_w   = (const float*)d_in[3];
  const float* conv_b   = (const float*)d_in[4];
  const float* W_gate   = (const float*)d_in[5];
  const float* W_a      = (const float*)d_in[6];
  const float* lam      = (const float*)d_in[7];
  const float* W_out    = (const float*)d_in[8];
  const float* b_out    = (const float*)d_in[9];
  const float* log_beta = (const float*)d_in[10];
  const float* ffn_w    = (const float*)d_in[11];
  const float* W_ff1    = (const float*)d_in[12];
  const float* b_ff1    = (const float*)d_in[13];
  const float* W_ff2    = (const float*)d_in[14];
  const float* b_ff2    = (const float*)d_in[15];

  float* out0 = (float*)d_out;   // x + ffn
  float* out1 = out0 + ND;       // velocity

  // Workspace layout (201 MB total), with lifetime-based aliasing:
  //   bufA: xnorm → mixer → x_new           [0,    ND)
  //   bufG: gate_pre → u → normed           [ND,  2ND)
  //   bufF: ffn mid (4*ND), overlays:       [2ND, 6ND)
  //     bufC = concat (2*ND)  @ bufF+0      (dead after W_out GEMM)
  //     bufP = a_pre → a (ND) @ bufF+2*ND   (dead after scan)
  float* bufA = (float*)d_ws;
  float* bufG = bufA + ND;
  float* bufF = bufG + ND;
  float* bufC = bufF;
  float* bufP = bufF + 2 * ND;

  const int EB = 256;
  const int egrid = (int)(ND / EB);  // 32768

  // 1. x_norm
  rmsnorm_k<<<Mm, 256, 0, stream>>>(x, pre_w, bufA);
  // 2. conv → concat[:, 0:D]
  conv_k<<<egrid, EB, 0, stream>>>(bufA, conv_w, conv_b, bufC);
  // 3. gate_pre / a_pre
  {
    dim3 g(Dd / 128, Mm / 128);
    sgemm_k<0><<<g, 256, 0, stream>>>(bufA, W_gate, bufG, Mm, Dd, Dd, nullptr, nullptr);
    sgemm_k<0><<<g, 256, 0, stream>>>(bufA, W_a,    bufP, Mm, Dd, Dd, nullptr, nullptr);
  }
  // 4. gating: bufG→u, bufP→a
  gating_k<<<egrid, EB, 0, stream>>>(bufG, bufP, bufA, lam);
  // 5. scan → concat[:, D:2D]
  scan_k<<<64, 64, 0, stream>>>(bufP, bufG, bufC);
  // 6. mixer = concat @ W_out + b_out  → bufA (xnorm dead)
  {
    dim3 g(Dd / 128, Mm / 128);
    sgemm_k<1><<<g, 256, 0, stream>>>(bufC, W_out, bufA, Mm, Dd, 2 * Dd, b_out, nullptr);
  }
  // 7. velocity update; bufA becomes x_new in place; out1 = new velocity
  vel_k<<<egrid, EB, 0, stream>>>(bufA, velocity, x, log_beta, out1);
  // 8. normed = rmsnorm(x_new) → bufG (u dead)
  rmsnorm_k<<<Mm, 256, 0, stream>>>(bufA, ffn_w, bufG);
  // 9. mid = gelu(normed @ W_ff1 + b_ff1) → bufF (overlays dead concat/a)
  {
    dim3 g(Ff / 128, Mm / 128);
    sgemm_k<3><<<g, 256, 0, stream>>>(bufG, W_ff1, bufF, Mm, Ff, Dd, b_ff1, nullptr);
  }
  // 10. out0 = mid @ W_ff2 + b_ff2 + x_new
  {
    dim3 g(Dd / 128, Mm / 128);
    sgemm_k<5><<<g, 256, 0, stream>>>(bufF, W_ff2, out0, Mm, Dd, Ff, b_ff2, bufA);
  }
}

// Round 2
// 856.326 us; speedup vs baseline: 3.3135x; 3.3135x over previous
//
#include <hip/hip_runtime.h>

// (B,S,D,K,F) = (4, 2048, 1024, 4, 4096)
static constexpr int Bb = 4;
static constexpr int Ss = 2048;
static constexpr int Dd = 1024;
static constexpr int Ff = 4096;
static constexpr int Mm = Bb * Ss;              // 8192 rows
static constexpr size_t ND = (size_t)Mm * Dd;   // 8388608

typedef __attribute__((ext_vector_type(8))) short short8;
typedef __attribute__((ext_vector_type(4))) float floatx4;

__device__ __forceinline__ unsigned f2bf(float f) {
  unsigned u = __builtin_bit_cast(unsigned, f);
  return (u + 0x7FFFu + ((u >> 16) & 1u)) >> 16;   // RNE
}
__device__ __forceinline__ float bf2f(unsigned bits) {
  return __builtin_bit_cast(float, bits << 16);
}
__device__ __forceinline__ void gload_lds16(const void* g, void* lds) {
  __builtin_amdgcn_global_load_lds((const __attribute__((address_space(1))) void*)g,
                                   (__attribute__((address_space(3))) void*)lds,
                                   16, 0, 0);
}

// ---------------- weight transpose + fp32->bf16: W[K][N] -> WT[N][K] --------
__global__ __launch_bounds__(256) void wconv_k(const float* __restrict__ W,
                                               unsigned short* __restrict__ WT,
                                               int K, int N) {
  __shared__ float tile[32][33];
  int tx = threadIdx.x & 31, ty = threadIdx.x >> 5;
  int bx = blockIdx.x * 32, by = blockIdx.y * 32;
#pragma unroll
  for (int i = 0; i < 32; i += 8)
    tile[ty + i][tx] = W[(size_t)(by + ty + i) * N + bx + tx];
  __syncthreads();
#pragma unroll
  for (int i = 0; i < 32; i += 8)
    WT[(size_t)(bx + ty + i) * K + by + tx] = (unsigned short)f2bf(tile[tx][ty + i]);
}

// ---------------- RMSNorm: fp32 in, bf16 out --------------------------------
__global__ __launch_bounds__(256) void rmsnorm_bf_k(const float* __restrict__ x,
                                                    const float* __restrict__ w,
                                                    unsigned short* __restrict__ out) {
  int row = blockIdx.x;
  const float4* xr = (const float4*)(x + (size_t)row * Dd);
  int t = threadIdx.x;
  float4 v = xr[t];
  float ss = v.x * v.x + v.y * v.y + v.z * v.z + v.w * v.w;
#pragma unroll
  for (int off = 32; off > 0; off >>= 1) ss += __shfl_down(ss, off, 64);
  __shared__ float sb[4];
  if ((t & 63) == 0) sb[t >> 6] = ss;
  __syncthreads();
  float tot = sb[0] + sb[1] + sb[2] + sb[3];
  float sc = rsqrtf(tot * (1.0f / (float)Dd) + 1e-6f);
  float4 wv = ((const float4*)w)[t];
  unsigned lo = f2bf(v.x * sc * wv.x) | (f2bf(v.y * sc * wv.y) << 16);
  unsigned hi = f2bf(v.z * sc * wv.z) | (f2bf(v.w * sc * wv.w) << 16);
  *(uint2*)(out + (size_t)row * Dd + t * 4) = make_uint2(lo, hi);
}

// ---------------- Causal depthwise conv (bf16 in/out) -> concat[:,0:D] ------
__global__ __launch_bounds__(256) void conv_k(const unsigned short* __restrict__ xn,
                                              const float* __restrict__ kern,
                                              const float* __restrict__ bias,
                                              unsigned short* __restrict__ outC) {
  size_t q = (size_t)blockIdx.x * 256 + threadIdx.x;  // over ND/4
  size_t i = q * 4;
  int d = (int)(i & (Dd - 1));
  int m = (int)(i >> 10);
  int t = m & (Ss - 1);
  float acc[4];
#pragma unroll
  for (int j = 0; j < 4; j++) acc[j] = bias[d + j];
#pragma unroll
  for (int k = 0; k < 4; k++) {
    if (t >= k) {
      uint2 xv = *(const uint2*)(xn + i - (size_t)k * Dd);
      float x0 = bf2f(xv.x & 0xFFFF), x1 = bf2f(xv.x >> 16);
      float x2 = bf2f(xv.y & 0xFFFF), x3 = bf2f(xv.y >> 16);
      acc[0] = fmaf(kern[(d + 0) * 4 + k], x0, acc[0]);
      acc[1] = fmaf(kern[(d + 1) * 4 + k], x1, acc[1]);
      acc[2] = fmaf(kern[(d + 2) * 4 + k], x2, acc[2]);
      acc[3] = fmaf(kern[(d + 3) * 4 + k], x3, acc[3]);
    }
  }
  unsigned lo = f2bf(acc[0]) | (f2bf(acc[1]) << 16);
  unsigned hi = f2bf(acc[2]) | (f2bf(acc[3]) << 16);
  *(uint2*)(outC + (size_t)m * (2 * Dd) + d) = make_uint2(lo, hi);
}

// ---------------- bf16 MFMA GEMM: C[M,N] = A[M,K] @ BT[N,K]^T ---------------
// 128x128 tile, BK=32, 256 thr (4 waves 2x2), 4x4 16x16x32 MFMA subtiles/wave.
// MODE bits: 1=+bias[col], 2=gelu(tanh), 4=+extra[row*N+col] (fp32), 8=bf16 out
template <int MODE>
__global__ __launch_bounds__(256) void bgemm_k(const unsigned short* __restrict__ A,
                                               const unsigned short* __restrict__ BT,
                                               void* __restrict__ Cout,
                                               int M, int N, int K,
                                               const float* __restrict__ bias,
                                               const float* __restrict__ extra) {
  __shared__ unsigned short As[128 * 32];
  __shared__ unsigned short Bs[128 * 32];
  const int tid = threadIdx.x;
  const int wave = tid >> 6, lane = tid & 63;
  const int r = lane & 15, quad = lane >> 4;
  const int wm = wave >> 1, wn = wave & 1;
  const int bm = blockIdx.y * 128, bn = blockIdx.x * 128;

  const unsigned short* Ab = A + (size_t)bm * K;
  const unsigned short* Bp = BT + (size_t)bn * K;
  const int srow = 32 * wave + (lane >> 2);   // staging row (chunk base)
  const int scol = (lane & 3) * 8;            // staging k-offset

  floatx4 acc[4][4];
#pragma unroll
  for (int i = 0; i < 4; i++)
#pragma unroll
    for (int j = 0; j < 4; j++) acc[i][j] = (floatx4){0.f, 0.f, 0.f, 0.f};

  for (int k0 = 0; k0 < K; k0 += 32) {
    __syncthreads();
    gload_lds16(Ab + (size_t)srow * K + k0 + scol,        As + wave * 1024);
    gload_lds16(Ab + (size_t)(srow + 16) * K + k0 + scol, As + wave * 1024 + 512);
    gload_lds16(Bp + (size_t)srow * K + k0 + scol,        Bs + wave * 1024);
    gload_lds16(Bp + (size_t)(srow + 16) * K + k0 + scol, Bs + wave * 1024 + 512);
    __syncthreads();
    short8 af[4], bfr[4];
#pragma unroll
    for (int i = 0; i < 4; i++)
      af[i] = *(const short8*)&As[(wm * 64 + i * 16 + r) * 32 + quad * 8];
#pragma unroll
    for (int j = 0; j < 4; j++)
      bfr[j] = *(const short8*)&Bs[(wn * 64 + j * 16 + r) * 32 + quad * 8];
#pragma unroll
    for (int i = 0; i < 4; i++)
#pragma unroll
      for (int j = 0; j < 4; j++)
        acc[i][j] = __builtin_amdgcn_mfma_f32_16x16x32_bf16(af[i], bfr[j], acc[i][j], 0, 0, 0);
  }

#pragma unroll
  for (int i = 0; i < 4; i++) {
#pragma unroll
    for (int j = 0; j < 4; j++) {
      int colg = bn + wn * 64 + j * 16 + r;
      float bv = (MODE & 1) ? bias[colg] : 0.0f;
#pragma unroll
      for (int reg = 0; reg < 4; reg++) {
        int rowg = bm + wm * 64 + i * 16 + quad * 4 + reg;
        float v = acc[i][j][reg] + bv;
        if (MODE & 2) {
          float c = v + 0.044715f * v * v * v;
          v = 0.5f * v * (1.0f + tanhf(0.7978845608028654f * c));
        }
        if (MODE & 4) v += extra[(size_t)rowg * N + colg];
        if (MODE & 8)
          ((unsigned short*)Cout)[(size_t)rowg * N + colg] = (unsigned short)f2bf(v);
        else
          ((float*)Cout)[(size_t)rowg * N + colg] = v;
      }
    }
  }
}

// ---------------- RG-LRU gating: gpre,apre fp32 -> u bf16, a fp32 (inplace) -
__global__ __launch_bounds__(256) void gating_k(const float* __restrict__ gpre,
                                                float* __restrict__ apre,
                                                const unsigned short* __restrict__ xn,
                                                const float* __restrict__ lam,
                                                unsigned short* __restrict__ ub) {
  size_t q = (size_t)blockIdx.x * 256 + threadIdx.x;
  size_t i = q * 4;
  int d = (int)(i & (Dd - 1));
  float4 gp = *(const float4*)(gpre + i);
  float4 ap = *(const float4*)(apre + i);
  float4 lm = *(const float4*)(lam + d);
  uint2 xv = *(const uint2*)(xn + i);
  float xf[4] = {bf2f(xv.x & 0xFFFF), bf2f(xv.x >> 16), bf2f(xv.y & 0xFFFF), bf2f(xv.y >> 16)};
  float gpv[4] = {gp.x, gp.y, gp.z, gp.w};
  float apv[4] = {ap.x, ap.y, ap.z, ap.w};
  float lmv[4] = {lm.x, lm.y, lm.z, lm.w};
  float av[4];
  unsigned ub4[4];
#pragma unroll
  for (int j = 0; j < 4; j++) {
    float g = 1.0f / (1.0f + expf(-gpv[j]));
    float sa = 1.0f / (1.0f + expf(-apv[j]));
    float l = lmv[j];
    float sp = fmaxf(l, 0.0f) + log1pf(expf(-fabsf(l)));
    float a = expf(-8.0f * sp * sa);
    float u = sqrtf(fmaxf(1.0f - a * a, 0.0f)) * g * xf[j];
    av[j] = a;
    ub4[j] = f2bf(u);
  }
  *(float4*)(apre + i) = make_float4(av[0], av[1], av[2], av[3]);
  *(uint2*)(ub + i) = make_uint2(ub4[0] | (ub4[1] << 16), ub4[2] | (ub4[3] << 16));
}

// ---------------- Sequential scan -> concat[:, D:2D] (bf16) -----------------
__global__ __launch_bounds__(64) void scan_k(const float* __restrict__ ab,
                                             const unsigned short* __restrict__ ub,
                                             unsigned short* __restrict__ outC) {
  int ch = blockIdx.x * 64 + threadIdx.x;  // 0..4095
  int b = ch >> 10;
  int e = ch & (Dd - 1);
  size_t base = (size_t)b * Ss * Dd + e;
  size_t ob = (size_t)b * Ss * (2 * Dd) + Dd + e;
  float h = 0.0f;
  for (int t = 0; t < Ss; t += 4) {
    size_t idx = base + (size_t)t * Dd;
    float a0 = ab[idx], a1 = ab[idx + Dd], a2 = ab[idx + 2 * Dd], a3 = ab[idx + 3 * Dd];
    float u0 = bf2f(ub[idx]), u1 = bf2f(ub[idx + Dd]);
    float u2 = bf2f(ub[idx + 2 * Dd]), u3 = bf2f(ub[idx + 3 * Dd]);
    size_t o = ob + (size_t)t * (2 * Dd);
    h = fmaf(a0, h, u0); outC[o] = (unsigned short)f2bf(h);
    h = fmaf(a1, h, u1); outC[o + 2 * Dd] = (unsigned short)f2bf(h);
    h = fmaf(a2, h, u2); outC[o + 4 * Dd] = (unsigned short)f2bf(h);
    h = fmaf(a3, h, u3); outC[o + 6 * Dd] = (unsigned short)f2bf(h);
  }
}

// ---------------- velocity update (mixer -> x_new in place) -----------------
__global__ __launch_bounds__(256) void vel_k(float* __restrict__ mixer_xnew,
                                             const float* __restrict__ velocity,
                                             const float* __restrict__ x,
                                             const float* __restrict__ log_beta,
                                             float* __restrict__ vel_out) {
  size_t q = (size_t)blockIdx.x * 256 + threadIdx.x;
  size_t i = q * 4;
  int d = (int)(i & (Dd - 1));
  float4 mx = *(const float4*)(mixer_xnew + i);
  float4 vo = *(const float4*)(velocity + i);
  float4 xo = *(const float4*)(x + i);
  float4 lb = *(const float4*)(log_beta + d);
  float4 vn, xn;
  vn.x = fmaf(1.0f / (1.0f + expf(-lb.x)), vo.x, mx.x);
  vn.y = fmaf(1.0f / (1.0f + expf(-lb.y)), vo.y, mx.y);
  vn.z = fmaf(1.0f / (1.0f + expf(-lb.z)), vo.z, mx.z);
  vn.w = fmaf(1.0f / (1.0f + expf(-lb.w)), vo.w, mx.w);
  xn.x = xo.x + vn.x; xn.y = xo.y + vn.y; xn.z = xo.z + vn.z; xn.w = xo.w + vn.w;
  *(float4*)(vel_out + i) = vn;
  *(float4*)(mixer_xnew + i) = xn;
}

extern "C" void kernel_launch(void* const* d_in, const int* in_sizes, int n_in,
                              void* d_out, int out_size, void* d_ws, size_t ws_size,
                              hipStream_t stream) {
  const float* x        = (const float*)d_in[0];
  const float* velocity = (const float*)d_in[1];
  const float* pre_w    = (const float*)d_in[2];
  const float* conv_w   = (const float*)d_in[3];
  const float* conv_b   = (const float*)d_in[4];
  const float* W_gate   = (const float*)d_in[5];
  const float* W_a      = (const float*)d_in[6];
  const float* lam      = (const float*)d_in[7];
  const float* W_out    = (const float*)d_in[8];
  const float* b_out    = (const float*)d_in[9];
  const float* log_beta = (const float*)d_in[10];
  const float* ffn_w    = (const float*)d_in[11];
  const float* W_ff1    = (const float*)d_in[12];
  const float* b_ff1    = (const float*)d_in[13];
  const float* W_ff2    = (const float*)d_in[14];
  const float* b_ff2    = (const float*)d_in[15];

  float* out0 = (float*)d_out;
  float* out1 = out0 + ND;

  // ---- workspace layout (byte offsets), lifetime-aliased; peak 184 MB ----
  const size_t MB = 1024 * 1024;
  char* ws = (char*)d_ws;
  unsigned short* WgT   = (unsigned short*)ws;                  // 1M el  [0,2MB)
  unsigned short* WaT   = WgT + (size_t)1024 * 1024;            // 1M el  [2,4)
  unsigned short* WoT   = WaT + (size_t)1024 * 1024;            // 2M el  [4,8)
  unsigned short* Wf1T  = WoT + (size_t)2 * 1024 * 1024;        // 4M el  [8,16)
  unsigned short* Wf2T  = Wf1T + (size_t)4 * 1024 * 1024;       // 4M el  [16,24)
  float*          mixer = (float*)(ws + 24 * MB);               // 32 MB  [24,56)
  unsigned short* conc  = (unsigned short*)(ws + 56 * MB);      // 32 MB  [56,88)
  float*          gpre  = (float*)(ws + 88 * MB);               // 32 MB  [88,120)
  float*          apre  = (float*)(ws + 120 * MB);              // 32 MB  [120,152)
  unsigned short* xnbf  = (unsigned short*)(ws + 152 * MB);     // 16 MB  [152,168)
  unsigned short* ubf   = (unsigned short*)(ws + 168 * MB);     // 16 MB  [168,184)
  unsigned short* midbf = (unsigned short*)(ws + 88 * MB);      // 64 MB overlay [88,152)
  unsigned short* nrmbf = (unsigned short*)(ws + 152 * MB);     // overlay xnbf

  const int EB = 256;
  const int egrid4 = (int)(ND / 4 / EB);  // vectorized-by-4 elementwise grid

  // 0. weight transpose + bf16 convert
  wconv_k<<<dim3(32, 32),  256, 0, stream>>>(W_gate, WgT, 1024, 1024);
  wconv_k<<<dim3(32, 32),  256, 0, stream>>>(W_a,    WaT, 1024, 1024);
  wconv_k<<<dim3(32, 64),  256, 0, stream>>>(W_out,  WoT, 2048, 1024);
  wconv_k<<<dim3(128, 32), 256, 0, stream>>>(W_ff1,  Wf1T, 1024, 4096);
  wconv_k<<<dim3(32, 128), 256, 0, stream>>>(W_ff2,  Wf2T, 4096, 1024);
  // 1. x_norm (bf16)
  rmsnorm_bf_k<<<Mm, 256, 0, stream>>>(x, pre_w, xnbf);
  // 2. conv -> concat[:, 0:D]
  conv_k<<<egrid4, EB, 0, stream>>>(xnbf, conv_w, conv_b, conc);
  // 3. gate_pre / a_pre (fp32 out)
  bgemm_k<0><<<dim3(8, 64), 256, 0, stream>>>(xnbf, WgT, gpre, Mm, 1024, 1024, nullptr, nullptr);
  bgemm_k<0><<<dim3(8, 64), 256, 0, stream>>>(xnbf, WaT, apre, Mm, 1024, 1024, nullptr, nullptr);
  // 4. gating: -> u (bf16), a (fp32, in place)
  gating_k<<<egrid4, EB, 0, stream>>>(gpre, apre, xnbf, lam, ubf);
  // 5. scan -> concat[:, D:2D]
  scan_k<<<64, 64, 0, stream>>>(apre, ubf, conc);
  // 6. mixer = concat @ W_out + b_out (fp32)
  bgemm_k<1><<<dim3(8, 64), 256, 0, stream>>>(conc, WoT, mixer, Mm, 1024, 2048, b_out, nullptr);
  // 7. velocity update; mixer becomes x_new in place
  vel_k<<<egrid4, EB, 0, stream>>>(mixer, velocity, x, log_beta, out1);
  // 8. normed = rmsnorm(x_new) (bf16)
  rmsnorm_bf_k<<<Mm, 256, 0, stream>>>(mixer, ffn_w, nrmbf);
  // 9. mid = gelu(normed @ W_ff1 + b_ff1) (bf16)
  bgemm_k<1 | 2 | 8><<<dim3(32, 64), 256, 0, stream>>>(nrmbf, Wf1T, midbf, Mm, 4096, 1024, b_ff1, nullptr);
  // 10. out0 = mid @ W_ff2 + b_ff2 + x_new (fp32)
  bgemm_k<1 | 4><<<dim3(8, 64), 256, 0, stream>>>(midbf, Wf2T, out0, Mm, 1024, 4096, b_ff2, mixer);
}

// Round 3
// 662.232 us; speedup vs baseline: 4.2846x; 1.2931x over previous
//
#include <hip/hip_runtime.h>

// (B,S,D,K,F) = (4, 2048, 1024, 4, 4096)
static constexpr int Bb = 4;
static constexpr int Ss = 2048;
static constexpr int Dd = 1024;
static constexpr int Ff = 4096;
static constexpr int Mm = Bb * Ss;              // 8192 rows
static constexpr size_t ND = (size_t)Mm * Dd;   // 8388608
static constexpr int CH = 32;                   // scan chunks
static constexpr int CL = Ss / CH;              // chunk length 64

typedef __attribute__((ext_vector_type(8))) short short8;
typedef __attribute__((ext_vector_type(4))) float floatx4;

__device__ __forceinline__ unsigned f2bf(float f) {
  unsigned u = __builtin_bit_cast(unsigned, f);
  return (u + 0x7FFFu + ((u >> 16) & 1u)) >> 16;   // RNE
}
__device__ __forceinline__ float bf2f(unsigned bits) {
  return __builtin_bit_cast(float, bits << 16);
}
__device__ __forceinline__ void gload_lds16(const void* g, void* lds) {
  __builtin_amdgcn_global_load_lds((const __attribute__((address_space(1))) void*)g,
                                   (__attribute__((address_space(3))) void*)lds,
                                   16, 0, 0);
}

// ---------------- weight transpose + fp32->bf16: W[K][N] -> WT[N][K] --------
__global__ __launch_bounds__(256) void wconv_k(const float* __restrict__ W,
                                               unsigned short* __restrict__ WT,
                                               int K, int N) {
  __shared__ float tile[32][33];
  int tx = threadIdx.x & 31, ty = threadIdx.x >> 5;
  int bx = blockIdx.x * 32, by = blockIdx.y * 32;
#pragma unroll
  for (int i = 0; i < 32; i += 8)
    tile[ty + i][tx] = W[(size_t)(by + ty + i) * N + bx + tx];
  __syncthreads();
#pragma unroll
  for (int i = 0; i < 32; i += 8)
    WT[(size_t)(bx + ty + i) * K + by + tx] = (unsigned short)f2bf(tile[tx][ty + i]);
}

// ---------------- RMSNorm: fp32 in, bf16 out --------------------------------
__global__ __launch_bounds__(256) void rmsnorm_bf_k(const float* __restrict__ x,
                                                    const float* __restrict__ w,
                                                    unsigned short* __restrict__ out) {
  int row = blockIdx.x;
  const float4* xr = (const float4*)(x + (size_t)row * Dd);
  int t = threadIdx.x;
  float4 v = xr[t];
  float ss = v.x * v.x + v.y * v.y + v.z * v.z + v.w * v.w;
#pragma unroll
  for (int off = 32; off > 0; off >>= 1) ss += __shfl_down(ss, off, 64);
  __shared__ float sb[4];
  if ((t & 63) == 0) sb[t >> 6] = ss;
  __syncthreads();
  float tot = sb[0] + sb[1] + sb[2] + sb[3];
  float sc = rsqrtf(tot * (1.0f / (float)Dd) + 1e-6f);
  float4 wv = ((const float4*)w)[t];
  unsigned lo = f2bf(v.x * sc * wv.x) | (f2bf(v.y * sc * wv.y) << 16);
  unsigned hi = f2bf(v.z * sc * wv.z) | (f2bf(v.w * sc * wv.w) << 16);
  *(uint2*)(out + (size_t)row * Dd + t * 4) = make_uint2(lo, hi);
}

// ---------------- Causal depthwise conv (bf16 in/out) -> concat[:,0:D] ------
__global__ __launch_bounds__(256) void conv_k(const unsigned short* __restrict__ xn,
                                              const float* __restrict__ kern,
                                              const float* __restrict__ bias,
                                              unsigned short* __restrict__ outC) {
  size_t q = (size_t)blockIdx.x * 256 + threadIdx.x;  // over ND/4
  size_t i = q * 4;
  int d = (int)(i & (Dd - 1));
  int m = (int)(i >> 10);
  int t = m & (Ss - 1);
  float acc[4];
#pragma unroll
  for (int j = 0; j < 4; j++) acc[j] = bias[d + j];
#pragma unroll
  for (int k = 0; k < 4; k++) {
    if (t >= k) {
      uint2 xv = *(const uint2*)(xn + i - (size_t)k * Dd);
      float x0 = bf2f(xv.x & 0xFFFF), x1 = bf2f(xv.x >> 16);
      float x2 = bf2f(xv.y & 0xFFFF), x3 = bf2f(xv.y >> 16);
      acc[0] = fmaf(kern[(d + 0) * 4 + k], x0, acc[0]);
      acc[1] = fmaf(kern[(d + 1) * 4 + k], x1, acc[1]);
      acc[2] = fmaf(kern[(d + 2) * 4 + k], x2, acc[2]);
      acc[3] = fmaf(kern[(d + 3) * 4 + k], x3, acc[3]);
    }
  }
  unsigned lo = f2bf(acc[0]) | (f2bf(acc[1]) << 16);
  unsigned hi = f2bf(acc[2]) | (f2bf(acc[3]) << 16);
  *(uint2*)(outC + (size_t)m * (2 * Dd) + d) = make_uint2(lo, hi);
}

// ---------------- bf16 MFMA GEMM: C[M,N] = A[M,K] @ BT[N,K]^T ---------------
// 128x128 tile, BK=32, 256 thr (4 waves 2x2), 4x4 16x16x32 MFMA subtiles/wave.
// MODE bits: 1=+bias[col], 2=gelu, 4=+extra (fp32), 8=bf16 out, 16=velocity
template <int MODE>
__global__ __launch_bounds__(256) void bgemm_k(const unsigned short* __restrict__ A,
                                               const unsigned short* __restrict__ BT,
                                               void* __restrict__ Cout,
                                               int M, int N, int K,
                                               const float* __restrict__ bias,
                                               const float* __restrict__ extra,
                                               const float* __restrict__ vel_in,
                                               const float* __restrict__ x_in,
                                               const float* __restrict__ log_beta,
                                               float* __restrict__ vel_out) {
  __shared__ unsigned short As[128 * 32];
  __shared__ unsigned short Bs[128 * 32];
  const int tid = threadIdx.x;
  const int wave = tid >> 6, lane = tid & 63;
  const int r = lane & 15, quad = lane >> 4;
  const int wm = wave >> 1, wn = wave & 1;
  const int bm = blockIdx.y * 128, bn = blockIdx.x * 128;

  const unsigned short* Ab = A + (size_t)bm * K;
  const unsigned short* Bp = BT + (size_t)bn * K;
  const int srow = 32 * wave + (lane >> 2);   // staging row (chunk base)
  const int scol = (lane & 3) * 8;            // staging k-offset

  floatx4 acc[4][4];
#pragma unroll
  for (int i = 0; i < 4; i++)
#pragma unroll
    for (int j = 0; j < 4; j++) acc[i][j] = (floatx4){0.f, 0.f, 0.f, 0.f};

  for (int k0 = 0; k0 < K; k0 += 32) {
    __syncthreads();
    gload_lds16(Ab + (size_t)srow * K + k0 + scol,        As + wave * 1024);
    gload_lds16(Ab + (size_t)(srow + 16) * K + k0 + scol, As + wave * 1024 + 512);
    gload_lds16(Bp + (size_t)srow * K + k0 + scol,        Bs + wave * 1024);
    gload_lds16(Bp + (size_t)(srow + 16) * K + k0 + scol, Bs + wave * 1024 + 512);
    __syncthreads();
    short8 af[4], bfr[4];
#pragma unroll
    for (int i = 0; i < 4; i++)
      af[i] = *(const short8*)&As[(wm * 64 + i * 16 + r) * 32 + quad * 8];
#pragma unroll
    for (int j = 0; j < 4; j++)
      bfr[j] = *(const short8*)&Bs[(wn * 64 + j * 16 + r) * 32 + quad * 8];
#pragma unroll
    for (int i = 0; i < 4; i++)
#pragma unroll
      for (int j = 0; j < 4; j++)
        acc[i][j] = __builtin_amdgcn_mfma_f32_16x16x32_bf16(af[i], bfr[j], acc[i][j], 0, 0, 0);
  }

#pragma unroll
  for (int i = 0; i < 4; i++) {
#pragma unroll
    for (int j = 0; j < 4; j++) {
      int colg = bn + wn * 64 + j * 16 + r;
      float bv = (MODE & 1) ? bias[colg] : 0.0f;
      float beta = (MODE & 16) ? 1.0f / (1.0f + expf(-log_beta[colg])) : 0.0f;
#pragma unroll
      for (int reg = 0; reg < 4; reg++) {
        int rowg = bm + wm * 64 + i * 16 + quad * 4 + reg;
        size_t idx = (size_t)rowg * N + colg;
        float v = acc[i][j][reg] + bv;
        if (MODE & 2) {
          float c = v + 0.044715f * v * v * v;
          v = 0.5f * v * (1.0f + tanhf(0.7978845608028654f * c));
        }
        if (MODE & 4) v += extra[idx];
        if (MODE & 16) {
          float vn = fmaf(beta, vel_in[idx], v);
          vel_out[idx] = vn;
          v = x_in[idx] + vn;          // x_new
        }
        if (MODE & 8)
          ((unsigned short*)Cout)[idx] = (unsigned short)f2bf(v);
        else
          ((float*)Cout)[idx] = v;
      }
    }
  }
}

// ---------------- scan phase 1: gating + per-chunk (A, h_local) -------------
__global__ __launch_bounds__(256) void scan_p1(const unsigned short* __restrict__ gpre,
                                               const unsigned short* __restrict__ apre,
                                               const unsigned short* __restrict__ xn,
                                               const float* __restrict__ lam,
                                               unsigned short* __restrict__ ub,
                                               float* __restrict__ carryA,
                                               float* __restrict__ carryH) {
  int g = blockIdx.x * 256 + threadIdx.x;    // 0..131071
  int e = g & (Dd - 1);
  int bc = g >> 10;
  int b = bc & 3;
  int c = bc >> 2;
  float l = lam[e];
  float sp = fmaxf(l, 0.0f) + log1pf(expf(-fabsf(l)));
  float m8sp = -8.0f * sp;
  size_t base = ((size_t)b * Ss + (size_t)c * CL) * Dd + e;
  float A = 1.0f, h = 0.0f;
#pragma unroll 4
  for (int t = 0; t < CL; t++) {
    size_t idx = base + (size_t)t * Dd;
    float ap = bf2f(apre[idx]);
    float gp = bf2f(gpre[idx]);
    float xv = bf2f(xn[idx]);
    float sa = 1.0f / (1.0f + expf(-ap));
    float a = expf(m8sp * sa);
    float gg = 1.0f / (1.0f + expf(-gp));
    float u = sqrtf(fmaxf(1.0f - a * a, 0.0f)) * gg * xv;
    ub[idx] = (unsigned short)f2bf(u);
    A *= a;
    h = fmaf(a, h, u);
  }
  carryA[c * 4096 + b * 1024 + e] = A;
  carryH[c * 4096 + b * 1024 + e] = h;
}

// ---------------- scan phase 2: scan carries -> per-chunk init state --------
__global__ __launch_bounds__(256) void scan_p2(const float* __restrict__ carryA,
                                               const float* __restrict__ carryH,
                                               float* __restrict__ init) {
  int ch = blockIdx.x * 256 + threadIdx.x;   // 0..4095
  float H = 0.0f;
#pragma unroll
  for (int c = 0; c < CH; c++) {
    init[c * 4096 + ch] = H;
    H = fmaf(carryA[c * 4096 + ch], H, carryH[c * 4096 + ch]);
  }
}

// ---------------- scan phase 3: rescan chunk with init -> concat[:,D:2D] ----
__global__ __launch_bounds__(256) void scan_p3(const unsigned short* __restrict__ apre,
                                               const unsigned short* __restrict__ ub,
                                               const float* __restrict__ lam,
                                               const float* __restrict__ init,
                                               unsigned short* __restrict__ outC) {
  int g = blockIdx.x * 256 + threadIdx.x;
  int e = g & (Dd - 1);
  int bc = g >> 10;
  int b = bc & 3;
  int c = bc >> 2;
  float l = lam[e];
  float sp = fmaxf(l, 0.0f) + log1pf(expf(-fabsf(l)));
  float m8sp = -8.0f * sp;
  size_t base = ((size_t)b * Ss + (size_t)c * CL) * Dd + e;
  size_t ob = ((size_t)b * Ss + (size_t)c * CL) * (2 * Dd) + Dd + e;
  float h = init[c * 4096 + b * 1024 + e];
#pragma unroll 4
  for (int t = 0; t < CL; t++) {
    size_t idx = base + (size_t)t * Dd;
    float ap = bf2f(apre[idx]);
    float sa = 1.0f / (1.0f + expf(-ap));
    float a = expf(m8sp * sa);
    float u = bf2f(ub[idx]);
    h = fmaf(a, h, u);
    outC[ob + (size_t)t * (2 * Dd)] = (unsigned short)f2bf(h);
  }
}

extern "C" void kernel_launch(void* const* d_in, const int* in_sizes, int n_in,
                              void* d_out, int out_size, void* d_ws, size_t ws_size,
                              hipStream_t stream) {
  const float* x        = (const float*)d_in[0];
  const float* velocity = (const float*)d_in[1];
  const float* pre_w    = (const float*)d_in[2];
  const float* conv_w   = (const float*)d_in[3];
  const float* conv_b   = (const float*)d_in[4];
  const float* W_gate   = (const float*)d_in[5];
  const float* W_a      = (const float*)d_in[6];
  const float* lam      = (const float*)d_in[7];
  const float* W_out    = (const float*)d_in[8];
  const float* b_out    = (const float*)d_in[9];
  const float* log_beta = (const float*)d_in[10];
  const float* ffn_w    = (const float*)d_in[11];
  const float* W_ff1    = (const float*)d_in[12];
  const float* b_ff1    = (const float*)d_in[13];
  const float* W_ff2    = (const float*)d_in[14];
  const float* b_ff2    = (const float*)d_in[15];

  float* out0 = (float*)d_out;
  float* out1 = out0 + ND;

  // ---- workspace (byte offsets), lifetime-aliased; peak 152 MB ----
  const size_t MB = 1024 * 1024;
  char* ws = (char*)d_ws;
  unsigned short* WgT   = (unsigned short*)ws;               // [0,2)
  unsigned short* WaT   = WgT + (size_t)1024 * 1024;         // [2,4)
  unsigned short* WoT   = WaT + (size_t)1024 * 1024;         // [4,8)
  unsigned short* Wf1T  = WoT + (size_t)2 * 1024 * 1024;     // [8,16)
  unsigned short* Wf2T  = Wf1T + (size_t)4 * 1024 * 1024;    // [16,24)
  float*          mixer = (float*)(ws + 24 * MB);            // 32 MB [24,56) — x_new
  float*          carA  = (float*)(ws + 24 * MB);            // 0.5 MB overlay (pre-step-6)
  float*          carH  = (float*)(ws + 24 * MB + 512 * 1024);
  float*          initb = (float*)(ws + 25 * MB);
  unsigned short* conc  = (unsigned short*)(ws + 56 * MB);   // 32 MB [56,88)
  unsigned short* gpre  = (unsigned short*)(ws + 88 * MB);   // 16 MB [88,104)
  unsigned short* apre  = (unsigned short*)(ws + 104 * MB);  // 16 MB [104,120)
  unsigned short* xnbf  = (unsigned short*)(ws + 120 * MB);  // 16 MB [120,136)
  unsigned short* ubf   = (unsigned short*)(ws + 136 * MB);  // 16 MB [136,152)
  unsigned short* midbf = (unsigned short*)(ws + 88 * MB);   // 64 MB overlay [88,152)
  unsigned short* nrmbf = (unsigned short*)(ws + 56 * MB);   // 16 MB overlay conc

  const int EB = 256;
  const int egrid4 = (int)(ND / 4 / EB);

  // 0. weight transpose + bf16 convert
  wconv_k<<<dim3(32, 32),  256, 0, stream>>>(W_gate, WgT, 1024, 1024);
  wconv_k<<<dim3(32, 32),  256, 0, stream>>>(W_a,    WaT, 1024, 1024);
  wconv_k<<<dim3(32, 64),  256, 0, stream>>>(W_out,  WoT, 2048, 1024);
  wconv_k<<<dim3(128, 32), 256, 0, stream>>>(W_ff1,  Wf1T, 1024, 4096);
  wconv_k<<<dim3(32, 128), 256, 0, stream>>>(W_ff2,  Wf2T, 4096, 1024);
  // 1. x_norm (bf16)
  rmsnorm_bf_k<<<Mm, 256, 0, stream>>>(x, pre_w, xnbf);
  // 2. conv -> concat[:, 0:D]
  conv_k<<<egrid4, EB, 0, stream>>>(xnbf, conv_w, conv_b, conc);
  // 3. gate_pre / a_pre (bf16 out)
  bgemm_k<8><<<dim3(8, 64), 256, 0, stream>>>(xnbf, WgT, gpre, Mm, 1024, 1024,
      nullptr, nullptr, nullptr, nullptr, nullptr, nullptr);
  bgemm_k<8><<<dim3(8, 64), 256, 0, stream>>>(xnbf, WaT, apre, Mm, 1024, 1024,
      nullptr, nullptr, nullptr, nullptr, nullptr, nullptr);
  // 4-5. chunked scan (gating fused into P1) -> concat[:, D:2D]
  scan_p1<<<512, 256, 0, stream>>>(gpre, apre, xnbf, lam, ubf, carA, carH);
  scan_p2<<<16, 256, 0, stream>>>(carA, carH, initb);
  scan_p3<<<512, 256, 0, stream>>>(apre, ubf, lam, initb, conc);
  // 6. mixer GEMM + fused velocity/x_new epilogue: mixer=x_new, out1=velocity
  bgemm_k<1 | 16><<<dim3(8, 64), 256, 0, stream>>>(conc, WoT, mixer, Mm, 1024, 2048,
      b_out, nullptr, velocity, x, log_beta, out1);
  // 8. normed = rmsnorm(x_new) (bf16)
  rmsnorm_bf_k<<<Mm, 256, 0, stream>>>(mixer, ffn_w, nrmbf);
  // 9. mid = gelu(normed @ W_ff1 + b_ff1) (bf16)
  bgemm_k<1 | 2 | 8><<<dim3(32, 64), 256, 0, stream>>>(nrmbf, Wf1T, midbf, Mm, 4096, 1024,
      b_ff1, nullptr, nullptr, nullptr, nullptr, nullptr);
  // 10. out0 = mid @ W_ff2 + b_ff2 + x_new (fp32)
  bgemm_k<1 | 4><<<dim3(8, 64), 256, 0, stream>>>(midbf, Wf2T, out0, Mm, 1024, 4096,
      b_ff2, mixer, nullptr, nullptr, nullptr, nullptr);
}